// Round 1
// baseline (215.535 us; speedup 1.0000x reference)
//
#include <hip/hip_runtime.h>

// Fixed problem shape from setup_inputs():
//   x: [B=32, C=69, H=128, W=128] fp32, k=2, stride=2
//   out: [B=32, C=69, Ho=64, Wo=64] fp32
//   channels 0..63: 2x2 maxpool; 64..68: query-weighted stats
#define B_ 32
#define C_ 69
#define CS_ 64
#define H_ 128
#define W_ 128
#define HO_ 64
#define WO_ 64

__global__ __launch_bounds__(256) void spatial_pool_kernel(
        const float* __restrict__ x, float* __restrict__ out) {
    int t = blockIdx.x * blockDim.x + threadIdx.x;
    // t = b*HO*WO + ho*WO + wo ; wo fastest -> coalesced
    int wo = t & (WO_ - 1);
    int ho = (t >> 6) & (HO_ - 1);
    int b  = t >> 12;

    const float* xb = x + (size_t)b * C_ * H_ * W_;
    float*       ob = out + (size_t)b * C_ * HO_ * WO_;

    const int h0 = 2 * ho, w0 = 2 * wo;
    const size_t base0 = (size_t)h0 * W_ + w0;   // window row 0
    const size_t base1 = base0 + W_;             // window row 1
    const size_t ostride = (size_t)HO_ * WO_;
    const size_t opix = (size_t)ho * WO_ + wo;

    float S0 = 0.f, S1 = 0.f, S2 = 0.f, S3 = 0.f;  // per-window-pixel abs sums

    // --- pooled channels 0..63: accumulate S, write maxpool ---
    #pragma unroll 8
    for (int c = 0; c < CS_; ++c) {
        const float* xc = xb + (size_t)c * (H_ * W_);
        float2 r0 = *(const float2*)(xc + base0);
        float2 r1 = *(const float2*)(xc + base1);
        S0 += fabsf(r0.x); S1 += fabsf(r0.y);
        S2 += fabsf(r1.x); S3 += fabsf(r1.y);
        float m = fmaxf(fmaxf(r0.x, r0.y), fmaxf(r1.x, r1.y));
        ob[(size_t)c * ostride + opix] = m;
    }

    // --- tail channels 64..68: accumulate S, stash window values ---
    float sp[5][4];
    #pragma unroll
    for (int d = 0; d < 5; ++d) {
        const float* xc = xb + (size_t)(CS_ + d) * (H_ * W_);
        float2 r0 = *(const float2*)(xc + base0);
        float2 r1 = *(const float2*)(xc + base1);
        sp[d][0] = r0.x; sp[d][1] = r0.y; sp[d][2] = r1.x; sp[d][3] = r1.y;
        S0 += fabsf(r0.x); S1 += fabsf(r0.y);
        S2 += fabsf(r1.x); S3 += fabsf(r1.y);
    }

    // --- query weights (1/sqrt(cs) scale cancels) ---
    float inv = 1.0f / (S0 + S1 + S2 + S3);
    float q[4] = {S0 * inv, S1 * inv, S2 * inv, S3 * inv};

    // means over channels 64,65
    float m0 = 0.f, m1 = 0.f;
    #pragma unroll
    for (int j = 0; j < 4; ++j) {
        m0 += sp[0][j] * q[j];
        m1 += sp[1][j] * q[j];
    }

    // var = var1(ch 66/67) + query-weighted squared deviation of ch 64/65
    // covar = cov1(ch 68) + q^2-weighted cross deviation
    float v0 = 0.f, v1 = 0.f, cv = 0.f;
    #pragma unroll
    for (int j = 0; j < 4; ++j) {
        float d0 = sp[0][j] - m0;
        float d1 = sp[1][j] - m1;
        v0 += sp[2][j] * q[j] + d0 * d0 * q[j];
        v1 += sp[3][j] * q[j] + d1 * d1 * q[j];
        cv += sp[4][j] * q[j] + d0 * d1 * q[j] * q[j];
    }

    ob[(size_t)(CS_ + 0) * ostride + opix] = m0;
    ob[(size_t)(CS_ + 1) * ostride + opix] = m1;
    ob[(size_t)(CS_ + 2) * ostride + opix] = v0;
    ob[(size_t)(CS_ + 3) * ostride + opix] = v1;
    ob[(size_t)(CS_ + 4) * ostride + opix] = cv;
}

extern "C" void kernel_launch(void* const* d_in, const int* in_sizes, int n_in,
                              void* d_out, int out_size, void* d_ws, size_t ws_size,
                              hipStream_t stream) {
    const float* x = (const float*)d_in[0];
    float* out = (float*)d_out;
    const int total = B_ * HO_ * WO_;   // 131072 threads, one per output pixel
    const int block = 256;
    const int grid = (total + block - 1) / block;  // 512 blocks
    spatial_pool_kernel<<<grid, block, 0, stream>>>(x, out);
}

// Round 2
// 215.270 us; speedup vs baseline: 1.0012x; 1.0012x over previous
//
#include <hip/hip_runtime.h>

// Fixed problem shape from setup_inputs():
//   x: [B=32, C=69, H=128, W=128] fp32, k=2, stride=2
//   out: [B=32, C=69, Ho=64, Wo=64] fp32
//   channels 0..63: 2x2 maxpool; 64..68: query-weighted stats
#define B_ 32
#define C_ 69
#define CS_ 64
#define H_ 128
#define W_ 128
#define HO_ 64
#define WO_ 64
#define HW_ (H_ * W_)
#define OHW_ (HO_ * WO_)

// Block = one (b, ho) output row of 64 pixels, all 69 channels.
// 4 waves split the channel dim: w0..w2 -> 17 pooled channels each,
// w3 -> 13 pooled + 5 tail channels (stashed in LDS).
// Per-pixel |x| partial sums reduced across waves via LDS.
__global__ __launch_bounds__(256, 8) void spatial_pool_kernel(
        const float* __restrict__ x, float* __restrict__ out) {
    __shared__ float part[4][4][64];   // [wave][j][pixel] abs-sum partials
    __shared__ float tail[5][4][64];   // [tail ch][j][pixel] raw window values

    const int lane = threadIdx.x & 63;   // = wo
    const int w    = threadIdx.x >> 6;   // wave id 0..3
    const int blk  = blockIdx.x;         // = b*64 + ho
    const int ho   = blk & 63;
    const int b    = blk >> 6;

    const float* xb = x   + (size_t)b * (C_ * HW_);
    float*       ob = out + (size_t)b * (C_ * OHW_);

    const int base0 = (2 * ho) * W_ + 2 * lane;  // window row 0
    const int base1 = base0 + W_;                // window row 1
    const int opix  = ho * WO_ + lane;

    float S0 = 0.f, S1 = 0.f, S2 = 0.f, S3 = 0.f;

    const int cbeg = w * 17;
    const int cend_pooled = (w == 3) ? CS_ : (cbeg + 17);  // wave3: 13 pooled

    #pragma unroll 4
    for (int c = cbeg; c < cend_pooled; ++c) {
        const float* xc = xb + c * HW_;
        float2 r0 = *(const float2*)(xc + base0);
        float2 r1 = *(const float2*)(xc + base1);
        S0 += fabsf(r0.x); S1 += fabsf(r0.y);
        S2 += fabsf(r1.x); S3 += fabsf(r1.y);
        float m = fmaxf(fmaxf(r0.x, r0.y), fmaxf(r1.x, r1.y));
        ob[c * OHW_ + opix] = m;
    }

    if (w == 3) {  // wave-uniform branch, no divergence
        #pragma unroll
        for (int d = 0; d < 5; ++d) {
            const float* xc = xb + (CS_ + d) * HW_;
            float2 r0 = *(const float2*)(xc + base0);
            float2 r1 = *(const float2*)(xc + base1);
            tail[d][0][lane] = r0.x; tail[d][1][lane] = r0.y;
            tail[d][2][lane] = r1.x; tail[d][3][lane] = r1.y;
            S0 += fabsf(r0.x); S1 += fabsf(r0.y);
            S2 += fabsf(r1.x); S3 += fabsf(r1.y);
        }
    }

    part[w][0][lane] = S0; part[w][1][lane] = S1;
    part[w][2][lane] = S2; part[w][3][lane] = S3;
    __syncthreads();

    if (w == 0) {
        // total abs-sum per window pixel j (1/sqrt(cs) scale cancels in q)
        float q[4];
        float tot = 0.f;
        #pragma unroll
        for (int j = 0; j < 4; ++j) {
            q[j] = part[0][j][lane] + part[1][j][lane]
                 + part[2][j][lane] + part[3][j][lane];
            tot += q[j];
        }
        float inv = 1.0f / tot;
        #pragma unroll
        for (int j = 0; j < 4; ++j) q[j] *= inv;

        float sp0[4], sp1[4], sp2[4], sp3[4], sp4[4];
        #pragma unroll
        for (int j = 0; j < 4; ++j) {
            sp0[j] = tail[0][j][lane];
            sp1[j] = tail[1][j][lane];
            sp2[j] = tail[2][j][lane];
            sp3[j] = tail[3][j][lane];
            sp4[j] = tail[4][j][lane];
        }

        float m0 = 0.f, m1 = 0.f;
        #pragma unroll
        for (int j = 0; j < 4; ++j) {
            m0 += sp0[j] * q[j];
            m1 += sp1[j] * q[j];
        }

        float v0 = 0.f, v1 = 0.f, cv = 0.f;
        #pragma unroll
        for (int j = 0; j < 4; ++j) {
            float d0 = sp0[j] - m0;
            float d1 = sp1[j] - m1;
            v0 += sp2[j] * q[j] + d0 * d0 * q[j];
            v1 += sp3[j] * q[j] + d1 * d1 * q[j];
            cv += sp4[j] * q[j] + d0 * d1 * q[j] * q[j];
        }

        ob[(CS_ + 0) * OHW_ + opix] = m0;
        ob[(CS_ + 1) * OHW_ + opix] = m1;
        ob[(CS_ + 2) * OHW_ + opix] = v0;
        ob[(CS_ + 3) * OHW_ + opix] = v1;
        ob[(CS_ + 4) * OHW_ + opix] = cv;
    }
}

extern "C" void kernel_launch(void* const* d_in, const int* in_sizes, int n_in,
                              void* d_out, int out_size, void* d_ws, size_t ws_size,
                              hipStream_t stream) {
    const float* x = (const float*)d_in[0];
    float* out = (float*)d_out;
    const int grid = B_ * HO_;   // 2048 blocks: one per (b, ho) output row
    spatial_pool_kernel<<<grid, 256, 0, stream>>>(x, out);
}

// Round 3
// 214.776 us; speedup vs baseline: 1.0035x; 1.0023x over previous
//
#include <hip/hip_runtime.h>

// Fixed problem shape from setup_inputs():
//   x: [B=32, C=69, H=128, W=128] fp32, k=2, stride=2
//   out: [B=32, C=69, Ho=64, Wo=64] fp32
//   channels 0..63: 2x2 maxpool; 64..68: query-weighted stats
#define B_ 32
#define C_ 69
#define CS_ 64
#define H_ 128
#define W_ 128
#define HO_ 64
#define WO_ 64
#define HW_ (H_ * W_)
#define OHW_ (HO_ * WO_)

// One thread = 2 adjacent output pixels (input cols 4p..4p+3 -> one float4
// per window row). Wave: lanes 0..31 -> output row ho, lanes 32..63 -> ho+1,
// so the float2 maxpool store is 512 B contiguous per wave. Block = 4 waves
// = 8 output rows; grid = 32 b x 8 row-groups = 256 blocks (1/CU).
__global__ __launch_bounds__(256) void spatial_pool_kernel(
        const float* __restrict__ x, float* __restrict__ out) {
    const int lane = threadIdx.x & 63;
    const int w    = threadIdx.x >> 6;       // wave 0..3
    const int p    = lane & 31;              // pixel-pair index (out cols 2p, 2p+1)
    const int rsel = lane >> 5;              // row within wave's row pair
    const int blk  = blockIdx.x;
    const int b    = blk >> 3;
    const int ho   = (blk & 7) * 8 + w * 2 + rsel;

    const float* xb = x   + (size_t)b * (C_ * HW_);
    float*       ob = out + (size_t)b * (C_ * OHW_);

    const int base0 = (2 * ho) * W_ + 4 * p;   // window row 0 (16B aligned)
    const int base1 = base0 + W_;              // window row 1
    const int opix  = ho * WO_ + 2 * p;

    // per-window-pixel |x| sums; a = pixel0 (cols 4p,4p+1), b = pixel1
    float Sa0 = 0.f, Sa1 = 0.f, Sa2 = 0.f, Sa3 = 0.f;
    float Sb0 = 0.f, Sb1 = 0.f, Sb2 = 0.f, Sb3 = 0.f;

    #pragma unroll 4
    for (int c = 0; c < CS_; ++c) {
        const float* xc = xb + c * HW_;
        float4 r0 = *(const float4*)(xc + base0);
        float4 r1 = *(const float4*)(xc + base1);
        Sa0 += fabsf(r0.x); Sa1 += fabsf(r0.y);
        Sa2 += fabsf(r1.x); Sa3 += fabsf(r1.y);
        Sb0 += fabsf(r0.z); Sb1 += fabsf(r0.w);
        Sb2 += fabsf(r1.z); Sb3 += fabsf(r1.w);
        float2 m;
        m.x = fmaxf(fmaxf(r0.x, r0.y), fmaxf(r1.x, r1.y));
        m.y = fmaxf(fmaxf(r0.z, r0.w), fmaxf(r1.z, r1.w));
        *(float2*)(ob + c * OHW_ + opix) = m;
    }

    // tail channels 64..68: stash window values in registers
    float4 t0[5], t1[5];
    #pragma unroll
    for (int d = 0; d < 5; ++d) {
        const float* xc = xb + (CS_ + d) * HW_;
        t0[d] = *(const float4*)(xc + base0);
        t1[d] = *(const float4*)(xc + base1);
        Sa0 += fabsf(t0[d].x); Sa1 += fabsf(t0[d].y);
        Sa2 += fabsf(t1[d].x); Sa3 += fabsf(t1[d].y);
        Sb0 += fabsf(t0[d].z); Sb1 += fabsf(t0[d].w);
        Sb2 += fabsf(t1[d].z); Sb3 += fabsf(t1[d].w);
    }

    // ---- stats for both pixels (1/sqrt(cs) scale cancels in q) ----
    float2 res[5];
    #pragma unroll
    for (int pix = 0; pix < 2; ++pix) {
        float q0, q1, q2, q3;
        float v64[4], v65[4], v66[4], v67[4], v68[4];
        if (pix == 0) {
            q0 = Sa0; q1 = Sa1; q2 = Sa2; q3 = Sa3;
            #pragma unroll
            for (int d = 0; d < 1; ++d) {}  // (keep structure simple)
            v64[0] = t0[0].x; v64[1] = t0[0].y; v64[2] = t1[0].x; v64[3] = t1[0].y;
            v65[0] = t0[1].x; v65[1] = t0[1].y; v65[2] = t1[1].x; v65[3] = t1[1].y;
            v66[0] = t0[2].x; v66[1] = t0[2].y; v66[2] = t1[2].x; v66[3] = t1[2].y;
            v67[0] = t0[3].x; v67[1] = t0[3].y; v67[2] = t1[3].x; v67[3] = t1[3].y;
            v68[0] = t0[4].x; v68[1] = t0[4].y; v68[2] = t1[4].x; v68[3] = t1[4].y;
        } else {
            q0 = Sb0; q1 = Sb1; q2 = Sb2; q3 = Sb3;
            v64[0] = t0[0].z; v64[1] = t0[0].w; v64[2] = t1[0].z; v64[3] = t1[0].w;
            v65[0] = t0[1].z; v65[1] = t0[1].w; v65[2] = t1[1].z; v65[3] = t1[1].w;
            v66[0] = t0[2].z; v66[1] = t0[2].w; v66[2] = t1[2].z; v66[3] = t1[2].w;
            v67[0] = t0[3].z; v67[1] = t0[3].w; v67[2] = t1[3].z; v67[3] = t1[3].w;
            v68[0] = t0[4].z; v68[1] = t0[4].w; v68[2] = t1[4].z; v68[3] = t1[4].w;
        }
        float inv = 1.0f / (q0 + q1 + q2 + q3);
        float q[4] = {q0 * inv, q1 * inv, q2 * inv, q3 * inv};

        float m0 = 0.f, m1 = 0.f;
        #pragma unroll
        for (int j = 0; j < 4; ++j) {
            m0 += v64[j] * q[j];
            m1 += v65[j] * q[j];
        }
        float vv0 = 0.f, vv1 = 0.f, cv = 0.f;
        #pragma unroll
        for (int j = 0; j < 4; ++j) {
            float d0 = v64[j] - m0;
            float d1 = v65[j] - m1;
            vv0 += v66[j] * q[j] + d0 * d0 * q[j];
            vv1 += v67[j] * q[j] + d1 * d1 * q[j];
            cv  += v68[j] * q[j] + d0 * d1 * q[j] * q[j];
        }
        if (pix == 0) {
            res[0].x = m0; res[1].x = m1; res[2].x = vv0; res[3].x = vv1; res[4].x = cv;
        } else {
            res[0].y = m0; res[1].y = m1; res[2].y = vv0; res[3].y = vv1; res[4].y = cv;
        }
    }

    #pragma unroll
    for (int d = 0; d < 5; ++d)
        *(float2*)(ob + (CS_ + d) * OHW_ + opix) = res[d];
}

extern "C" void kernel_launch(void* const* d_in, const int* in_sizes, int n_in,
                              void* d_out, int out_size, void* d_ws, size_t ws_size,
                              hipStream_t stream) {
    const float* x = (const float*)d_in[0];
    float* out = (float*)d_out;
    const int grid = B_ * (HO_ / 8);   // 256 blocks, 256 threads, 2 pixels/thread
    spatial_pool_kernel<<<grid, 256, 0, stream>>>(x, out);
}